// Round 17
// baseline (335.855 us; speedup 1.0000x reference)
//
#include <hip/hip_runtime.h>
#include <hip/hip_bf16.h>
#include <math.h>

#define B_ 4
#define S_ 1024
#define H_ 512
#define NH_ 8
#define HD_ 64
#define FF_ 1024
#define E_ 4
#define L_ 4
#define NT_ 17
#define BS_ 4096
#define EPS_ 1e-5f
#define L2E_ 1.4426950408889634f
#define SCL_ 0.18033688011112042f   // 0.125 * log2(e)
#define KSPLIT_ 4

typedef __attribute__((ext_vector_type(8))) short short8;
typedef __attribute__((ext_vector_type(16))) float f32x16;
typedef float float4u __attribute__((ext_vector_type(4), aligned(4)));

__device__ inline ushort bf16_rne(float f) {
  unsigned u = __builtin_bit_cast(unsigned, f);
  u += 0x7FFFu + ((u >> 16) & 1u);
  return (ushort)(u >> 16);
}
__device__ inline unsigned pk_bf16(float a, float b) {
  return (unsigned)bf16_rne(a) | ((unsigned)bf16_rne(b) << 16);
}
// fast pack: round-half-away + v_perm_b32 (3 VALU ops)
__device__ inline unsigned pk2(float a, float b) {
  unsigned ua = __builtin_bit_cast(unsigned, a) + 0x8000u;
  unsigned ub = __builtin_bit_cast(unsigned, b) + 0x8000u;
  return __builtin_amdgcn_perm(ub, ua, 0x07060302u);
}
__device__ inline float ubf2f(ushort u) {
  return __builtin_bit_cast(float, ((unsigned)u) << 16);
}

// frag32 layout: a [32 rows]x[16 k] bf16 tile stored as 64 lanes x 8 ushort;
// lane (hh*32+lq) holds row lq, k = hh*8..hh*8+7.  One tile = 1024 B, loaded
// by a wave as a single coalesced 16B/lane read.  Serves both MFMA A and B
// operands of 32x32x16 (their lane->element maps coincide).

// ---------------------------------------------------------------------------
// k_pre: fused one-time prologue (block-range dispatch).
//   bid in [0,768):     cvtw — Wqkv fp32 -> Wt bf16 [l][n][k] (LDS transpose)
//   bid in [768,817):   init — x/negT/T tables
//   bid in [817,1841):  inln layer 0 — wave/token, direct emb gather
// ---------------------------------------------------------------------------
__global__ __launch_bounds__(256) void k_pre(const int* __restrict__ patches,
                                             const int* __restrict__ mask,
                                             const float* __restrict__ emb,
                                             const float* __restrict__ relemb,
                                             const float* __restrict__ W,
                                             const float* __restrict__ Wi,
                                             const float* __restrict__ bi,
                                             const float* __restrict__ g1,
                                             const float* __restrict__ b1n,
                                             float* __restrict__ x,
                                             float* __restrict__ T,
                                             float* __restrict__ negT,
                                             ushort* __restrict__ Wt,
                                             ushort* __restrict__ xnbf) {
  __shared__ ushort Tr[64][72];
  int bid = blockIdx.x, t = threadIdx.x;
  if (bid < 768) {
    int l = bid / 192, rem = bid % 192;
    int k0 = (rem / 24) * 64, n0 = (rem % 24) * 64;
    const float* src = W + (size_t)l * 512 * 1536;
    int row = t >> 4, c4 = (t & 15) * 4;
#pragma unroll
    for (int rr = 0; rr < 4; rr++) {
      int k = rr * 16 + row;
      float4 v = *(const float4*)(src + (size_t)(k0 + k) * 1536 + n0 + c4);
      Tr[c4 + 0][k] = bf16_rne(v.x);
      Tr[c4 + 1][k] = bf16_rne(v.y);
      Tr[c4 + 2][k] = bf16_rne(v.z);
      Tr[c4 + 3][k] = bf16_rne(v.w);
    }
    __syncthreads();
    int nrow = t >> 2, kc = (t & 3) * 16;
    ushort* dst = Wt + ((size_t)(l * 1536 + n0 + nrow)) * 512 + k0 + kc;
    *(uint4*)dst = *(uint4*)&Tr[nrow][kc];
    *(uint4*)(dst + 8) = *(uint4*)&Tr[nrow][kc + 8];
  } else if (bid < 817) {
    int gid = (bid - 768) * 256 + t;
    if (gid < BS_) {
      int mk = mask[gid];
      int row = mk ? (NT_ - 1) : patches[gid];
      ((float4*)x)[gid] = ((const float4*)emb)[row];
      negT[gid] = mk ? -1e30f : 0.f;
    } else {
      int idx = gid - BS_;
      if (idx < L_ * 2112) {
        int l = idx / 2112, j = idx - l * 2112;
        int c = 1086 - j;
        c = c < 0 ? 0 : (c > 62 ? 62 : c);
        const float* src = relemb + (size_t)(l * 63 + c) * 64;
        float s = 0.f;
#pragma unroll
        for (int d = 0; d < 64; d++) s += src[d];
        T[idx] = s * L2E_;
      }
    }
  } else {
    int token = (bid - 817) * 4 + (t >> 6);
    int lane = t & 63;
    int mk = mask[token];
    int row = mk ? (NT_ - 1) : patches[token];
    float4 e = ((const float4*)emb)[row];
    float xp[8];
    float s = 0.f, qs = 0.f;
#pragma unroll
    for (int k = 0; k < 8; k++) {
      int jj = 64 * k + lane;
      float v = bi[jj] + e.x * Wi[jj] + e.y * Wi[H_ + jj] + e.z * Wi[2 * H_ + jj] + e.w * Wi[3 * H_ + jj];
      xp[k] = v; s += v; qs += v * v;
    }
#pragma unroll
    for (int o = 1; o < 64; o <<= 1) { s += __shfl_xor(s, o); qs += __shfl_xor(qs, o); }
    float mean = s * (1.f / (float)H_);
    float var = qs * (1.f / (float)H_) - mean * mean;
    float rs = rsqrtf(var + EPS_);
#pragma unroll
    for (int k = 0; k < 8; k++) {
      int jj = 64 * k + lane;
      xnbf[token * H_ + jj] = bf16_rne((xp[k] - mean) * rs * g1[jj] + b1n[jj]);
    }
  }
}

// ---------------------------------------------------------------------------
// k_qkv: bf16 MFMA GEMM; 128x128 tile, BK=64.  Register-prefetch + double-
// buffered LDS, one barrier per K-step.  Epilogues write q/k/v frag32.
// ---------------------------------------------------------------------------
__global__ __launch_bounds__(256, 2) void k_qkv(const ushort* __restrict__ A,
                                                const ushort* __restrict__ Wt,
                                                const float* __restrict__ bias,
                                                ushort* __restrict__ qf,
                                                ushort* __restrict__ kf,
                                                ushort* __restrict__ vf) {
  __shared__ ushort At[2][128][72];
  __shared__ ushort Bt[2][128][72];
  int t = threadIdx.x;
  int n0 = blockIdx.x * 128, m0 = blockIdx.y * 128;
  bool tr = (n0 < 1024);
  int w = t >> 6, lq = t & 31, hh = (t >> 5) & 1;
  int wm = (w & 1) * 64, wn = (w >> 1) * 64;
  f32x16 acc[2][2];
#pragma unroll
  for (int mt = 0; mt < 2; mt++)
#pragma unroll
    for (int nt = 0; nt < 2; nt++)
#pragma unroll
      for (int i = 0; i < 16; i++) acc[mt][nt][i] = 0.f;

  uint4 ar[4], br[4];

#define QLOADREGS(k0_)                                                         \
  {                                                                            \
    _Pragma("unroll") for (int j = 0; j < 4; j++) {                            \
      int idl = 256 * j + t;                                                   \
      int row = idl >> 3, u = idl & 7;                                         \
      ar[j] = *(const uint4*)(A + (size_t)(m0 + row) * 512 + (k0_) + u * 8);   \
      br[j] = *(const uint4*)(Wt + (size_t)(n0 + row) * 512 + (k0_) + u * 8);  \
    }                                                                          \
  }
#define QWRITELDS(buf_)                                                        \
  {                                                                            \
    _Pragma("unroll") for (int j = 0; j < 4; j++) {                            \
      int idl = 256 * j + t;                                                   \
      int row = idl >> 3, u = idl & 7;                                         \
      *(uint4*)&At[buf_][row][u * 8] = ar[j];                                  \
      *(uint4*)&Bt[buf_][row][u * 8] = br[j];                                  \
    }                                                                          \
  }

  QLOADREGS(0);
  QWRITELDS(0);
  __syncthreads();

  for (int it = 0; it < 8; it++) {
    int buf = it & 1;
    if (it < 7) { QLOADREGS((it + 1) * 64); }
#pragma unroll
    for (int kc = 0; kc < 4; kc++) {
      short8 af[2], bf[2];
#pragma unroll
      for (int mt = 0; mt < 2; mt++) af[mt] = *(const short8*)&At[buf][wm + mt * 32 + lq][kc * 16 + hh * 8];
#pragma unroll
      for (int nt = 0; nt < 2; nt++) bf[nt] = *(const short8*)&Bt[buf][wn + nt * 32 + lq][kc * 16 + hh * 8];
#pragma unroll
      for (int mt = 0; mt < 2; mt++)
#pragma unroll
        for (int nt = 0; nt < 2; nt++) {
          if (tr)
            acc[mt][nt] = __builtin_amdgcn_mfma_f32_32x32x16_bf16(bf[nt], af[mt], acc[mt][nt], 0, 0, 0);
          else
            acc[mt][nt] = __builtin_amdgcn_mfma_f32_32x32x16_bf16(af[mt], bf[nt], acc[mt][nt], 0, 0, 0);
        }
    }
    if (it < 7) {
      QWRITELDS(buf ^ 1);
      __syncthreads();
    }
  }
#undef QLOADREGS
#undef QWRITELDS

  if (tr) {
#pragma unroll
    for (int mt = 0; mt < 2; mt++) {
      int token = m0 + wm + mt * 32 + lq;
      int bb = token >> 10, sr = token & 1023;
      int qt = sr >> 5, lqp = sr & 31;
#pragma unroll
      for (int nt = 0; nt < 2; nt++) {
        int nn = n0 + wn + nt * 32;
        int nloc = (nn < 512) ? nn : nn - 512;
        ushort* dst = (nn < 512) ? qf : kf;
        int hd = nloc >> 6;
        int bh = bb * 8 + hd;
        size_t fragbase = ((size_t)(bh * 32 + qt)) * 4 * 512;
#pragma unroll
        for (int rg = 0; rg < 4; rg++) {
          int nbase = nn + rg * 8 + hh * 4;
          float4 bv = *(const float4*)(bias + nbase);
          float v0 = acc[mt][nt][rg * 4 + 0] + bv.x;
          float v1 = acc[mt][nt][rg * 4 + 1] + bv.y;
          float v2 = acc[mt][nt][rg * 4 + 2] + bv.z;
          float v3 = acc[mt][nt][rg * 4 + 3] + bv.w;
          int d0 = (nloc & 63) + rg * 8 + hh * 4;
          size_t addr = fragbase + (size_t)(d0 >> 4) * 512 +
                        (size_t)(((d0 >> 3) & 1) * 32 + lqp) * 8 + (d0 & 7);
          *(uint2*)(dst + addr) = make_uint2(pk_bf16(v0, v1), pk_bf16(v2, v3));
        }
      }
    }
  } else {
#pragma unroll
    for (int nt = 0; nt < 2; nt++) {
      int n = n0 + wn + nt * 32 + lq;
      int nloc = n - 1024;
      int hd = nloc >> 6, d = nloc & 63;
      float bb_ = bias[n];
#pragma unroll
      for (int mt = 0; mt < 2; mt++) {
#pragma unroll
        for (int rg = 0; rg < 4; rg++) {
          int tb = m0 + wm + mt * 32 + rg * 8 + hh * 4;
          int bb = tb >> 10, sr = tb & 1023;
          int bh = bb * 8 + hd;
          float v0 = acc[mt][nt][rg * 4 + 0] + bb_;
          float v1 = acc[mt][nt][rg * 4 + 1] + bb_;
          float v2 = acc[mt][nt][rg * 4 + 2] + bb_;
          float v3 = acc[mt][nt][rg * 4 + 3] + bb_;
          size_t addr = ((size_t)((bh * 2 + (d >> 5)) * 64 + (sr >> 4))) * 512 +
                        (size_t)(((sr >> 3) & 1) * 32 + (d & 31)) * 8 + (sr & 7);
          *(uint2*)(vf + addr) = make_uint2(pk_bf16(v0, v1), pk_bf16(v2, v3));
        }
      }
    }
  }
}

// ---------------------------------------------------------------------------
// k_attn: bf16 MFMA attention, S^T form, fixed-scale softmax.  4 waves/block
// sharing a K/V chunk; KSPLIT=4 (1024 blocks), zero __syncthreads.
// SOFTWARE-PIPELINED K loads: K frags for tile it+1 are issued before the
// compute of tile it (register double-buffer) -- K is the critical chain
// (consumed immediately by QK MFMA); V keeps its natural softmax-phase slack.
// Epilogue fuses Wo; private j-slot float4 partials (no atomics).
// ---------------------------------------------------------------------------
__global__ __launch_bounds__(256, 3) void k_attn(const ushort* __restrict__ qf,
                                                 const ushort* __restrict__ kf,
                                                 const ushort* __restrict__ vf,
                                                 const float* __restrict__ Tl,
                                                 const float* __restrict__ negT,
                                                 const float* __restrict__ Wol,
                                                 float* __restrict__ AOp,
                                                 float* __restrict__ lpart) {
  __shared__ ushort Pt[4][32][72];
  int t = threadIdx.x;
  int w = t >> 6, lane = t & 63;
  int lq = lane & 31, hh = lane >> 5;
  int id = blockIdx.x;
  int bh = id & 31;
  int slot = id >> 5;
  int qtg = slot & 7, j = slot >> 3;
  int b = bh >> 3, head = bh & 7;
  int qt = qtg * 4 + w;
  int q = qt * 32 + lq;
  int kstart = j * 256;

  const ushort* qbase = qf + ((size_t)(bh * 32 + qt)) * 2048 + lane * 8;
  short8 Qf[4];
#pragma unroll
  for (int c = 0; c < 4; c++) Qf[c] = *(const short8*)(qbase + c * 512);

  float Tlo = Tl[1086];
  float Thi = Tl[1024];

  float l_run = 0.f;
  f32x16 Ot[2];
#pragma unroll
  for (int dt = 0; dt < 2; dt++)
#pragma unroll
    for (int i = 0; i < 16; i++) Ot[dt][i] = 0.f;

  short8 Kb[2][2][4];  // [buf][st][c] register double-buffer
#define LOADK(k0_, buf_)                                                      \
  {                                                                           \
    _Pragma("unroll") for (int st = 0; st < 2; st++) {                        \
      const ushort* kb =                                                      \
          kf + ((size_t)(bh * 32 + ((k0_) >> 5) + st)) * 2048 + lane * 8;     \
      _Pragma("unroll") for (int c = 0; c < 4; c++)                           \
          Kb[buf_][st][c] = *(const short8*)(kb + c * 512);                   \
    }                                                                         \
  }

  LOADK(kstart, 0);

#pragma unroll
  for (int it = 0; it < 4; it++) {
    int k0 = kstart + it * 64;
    int buf = it & 1;
    if (it < 3) { LOADK(k0 + 64, buf ^ 1); }  // prefetch next K tile
    short8 Vb[2][4];
#pragma unroll
    for (int dt = 0; dt < 2; dt++) {
      const ushort* vb = vf + ((size_t)((bh * 2 + dt) * 64 + (k0 >> 4))) * 512 + lane * 8;
#pragma unroll
      for (int c = 0; c < 4; c++) Vb[dt][c] = *(const short8*)(vb + c * 512);
    }
    // ---- S^T ----
    f32x16 sa[2];
#pragma unroll
    for (int st = 0; st < 2; st++) {
      f32x16 a;
#pragma unroll
      for (int i = 0; i < 16; i++) a[i] = 0.f;
#pragma unroll
      for (int c = 0; c < 4; c++)
        a = __builtin_amdgcn_mfma_f32_32x32x16_bf16(Kb[buf][st][c], Qf[c], a, 0, 0, 0);
      sa[st] = a;
    }
    // ---- softmax: band-specialized ----
#pragma unroll
    for (int st = 0; st < 2; st++) {
      int kt0 = k0 + st * 32;
      int delta = kt0 - qt * 32;
      if (delta >= 64 || delta <= -64) {
        float bconst = (delta >= 64) ? Tlo : Thi;
#pragma unroll
        for (int rg = 0; rg < 4; rg++) {
          int krun = kt0 + rg * 8 + hh * 4;
          float4 nv = *(const float4*)(negT + b * S_ + krun);
          float p0 = exp2f(fmaf(sa[st][rg * 4 + 0], SCL_, bconst + nv.x));
          float p1 = exp2f(fmaf(sa[st][rg * 4 + 1], SCL_, bconst + nv.y));
          float p2 = exp2f(fmaf(sa[st][rg * 4 + 2], SCL_, bconst + nv.z));
          float p3 = exp2f(fmaf(sa[st][rg * 4 + 3], SCL_, bconst + nv.w));
          l_run += (p0 + p1) + (p2 + p3);
          *(uint2*)&Pt[w][lq][st * 32 + rg * 8 + hh * 4] = make_uint2(pk2(p0, p1), pk2(p2, p3));
        }
      } else {
#pragma unroll
        for (int rg = 0; rg < 4; rg++) {
          int krun = kt0 + rg * 8 + hh * 4;
          float4u bv = *(const float4u*)(Tl + (krun - q + 31 + 1024));
          float4 nv = *(const float4*)(negT + b * S_ + krun);
          float p[4];
#pragma unroll
          for (int i = 0; i < 4; i++) {
            float nvi = (i == 0) ? nv.x : (i == 1) ? nv.y : (i == 2) ? nv.z : nv.w;
            float t0 = (krun + i == q) ? bv[i] : (bv[i] + nvi);
            p[i] = exp2f(fmaf(sa[st][rg * 4 + i], SCL_, t0));
            l_run += p[i];
          }
          *(uint2*)&Pt[w][lq][st * 32 + rg * 8 + hh * 4] = make_uint2(pk2(p[0], p[1]), pk2(p[2], p[3]));
        }
      }
    }
    // ---- O^T += V^T . P ----
    short8 Pf[4];
#pragma unroll
    for (int c = 0; c < 4; c++) Pf[c] = *(const short8*)&Pt[w][lq][c * 16 + hh * 8];
#pragma unroll
    for (int dt = 0; dt < 2; dt++)
#pragma unroll
      for (int c = 0; c < 4; c++)
        Ot[dt] = __builtin_amdgcn_mfma_f32_32x32x16_bf16(Vb[dt][c], Pf[c], Ot[dt], 0, 0, 0);
  }
#undef LOADK
  // ---- epilogue: project through Wo[head], store private j-slot partial ----
  const float* woh = Wol + head * 64 * 4;
  float pe0 = 0.f, pe1 = 0.f, pe2 = 0.f, pe3 = 0.f;
#pragma unroll
  for (int dt = 0; dt < 2; dt++)
#pragma unroll
    for (int rg = 0; rg < 4; rg++)
#pragma unroll
      for (int i = 0; i < 4; i++) {
        int d = dt * 32 + rg * 8 + hh * 4 + i;
        float4 wv = *(const float4*)(woh + d * 4);
        float o = Ot[dt][rg * 4 + i];
        pe0 = fmaf(o, wv.x, pe0);
        pe1 = fmaf(o, wv.y, pe1);
        pe2 = fmaf(o, wv.z, pe2);
        pe3 = fmaf(o, wv.w, pe3);
      }
  pe0 += __shfl_xor(pe0, 32);
  pe1 += __shfl_xor(pe1, 32);
  pe2 += __shfl_xor(pe2, 32);
  pe3 += __shfl_xor(pe3, 32);
  float l_tot = l_run + __shfl_xor(l_run, 32);
  if (hh == 0) {
    float* ao = AOp + (size_t)j * (BS_ * NH_ * 4) + ((size_t)(b * S_ + q) * NH_ + head) * 4;
    *(float4*)ao = make_float4(pe0, pe1, pe2, pe3);
    lpart[((size_t)j * 32 + bh) * S_ + q] = l_tot;
  }
}

// ---------------------------------------------------------------------------
// k_resffn: combine j-slot partials per head, sum heads, x += ao + bo,
// ln2(E=4), FFN, residual.  doinln: fuse next layer's inproj+LN.
// dofinal: out = x@Wout+bout.
// ---------------------------------------------------------------------------
__global__ __launch_bounds__(256) void k_resffn(const float* __restrict__ AOp,
                                                const float* __restrict__ lpart,
                                                const float* __restrict__ bo,
                                                const float* __restrict__ g2,
                                                const float* __restrict__ b2n,
                                                const float* __restrict__ Wf1,
                                                const float* __restrict__ bf1,
                                                const float* __restrict__ Wf2,
                                                const float* __restrict__ bf2,
                                                float* __restrict__ x,
                                                const float* __restrict__ Wi,
                                                const float* __restrict__ bi,
                                                const float* __restrict__ g1,
                                                const float* __restrict__ b1n,
                                                ushort* __restrict__ xnbf,
                                                int doinln,
                                                const float* __restrict__ Wout,
                                                const float* __restrict__ bout,
                                                float* __restrict__ out,
                                                int dofinal) {
  int tok = blockIdx.x * 4 + (threadIdx.x >> 6);
  int lane = threadIdx.x & 63;
  int b = tok >> 10, qq = tok & 1023;
  int h = lane & 7;
  int lidx = (b * 8 + h) * 1024 + qq;
  float ls = lpart[lidx] + lpart[lidx + 32768] + lpart[lidx + 65536] + lpart[lidx + 98304];
  float inv = 1.f / ls;
  size_t abase = ((size_t)tok * 8 + h) * 4;
  float4 v0 = *(const float4*)(AOp + abase);
  float4 v1 = *(const float4*)(AOp + abase + 131072);
  float4 v2 = *(const float4*)(AOp + abase + 262144);
  float4 v3 = *(const float4*)(AOp + abase + 393216);
  float r0 = (v0.x + v1.x + v2.x + v3.x) * inv;
  float r1 = (v0.y + v1.y + v2.y + v3.y) * inv;
  float r2 = (v0.z + v1.z + v2.z + v3.z) * inv;
  float r3 = (v0.w + v1.w + v2.w + v3.w) * inv;
#pragma unroll
  for (int o = 1; o < 8; o <<= 1) {
    r0 += __shfl_xor(r0, o); r1 += __shfl_xor(r1, o);
    r2 += __shfl_xor(r2, o); r3 += __shfl_xor(r3, o);
  }
  float4 xo = *(const float4*)&x[tok * 4];
  float x0 = xo.x + r0 + bo[0];
  float x1 = xo.y + r1 + bo[1];
  float x2 = xo.z + r2 + bo[2];
  float x3 = xo.w + r3 + bo[3];
  float mn = 0.25f * (x0 + x1 + x2 + x3);
  float d0 = x0 - mn, d1 = x1 - mn, d2 = x2 - mn, d3 = x3 - mn;
  float var = 0.25f * (d0 * d0 + d1 * d1 + d2 * d2 + d3 * d3);
  float rs = rsqrtf(var + EPS_);
  float l0 = d0 * rs * g2[0] + b2n[0];
  float l1 = d1 * rs * g2[1] + b2n[1];
  float l2 = d2 * rs * g2[2] + b2n[2];
  float l3 = d3 * rs * g2[3] + b2n[3];
  float f0 = 0, f1 = 0, f2 = 0, f3 = 0;
#pragma unroll
  for (int f4 = 0; f4 < FF_ / 64; f4++) {
    int f = lane + f4 * 64;
    float hh = bf1[f] + l0 * Wf1[f] + l1 * Wf1[FF_ + f] + l2 * Wf1[2 * FF_ + f] + l3 * Wf1[3 * FF_ + f];
    hh = fmaxf(hh, 0.f);
    float4 w2 = *(const float4*)&Wf2[f * 4];
    f0 += hh * w2.x; f1 += hh * w2.y; f2 += hh * w2.z; f3 += hh * w2.w;
  }
#pragma unroll
  for (int o = 1; o < 64; o <<= 1) {
    f0 += __shfl_xor(f0, o); f1 += __shfl_xor(f1, o);
    f2 += __shfl_xor(f2, o); f3 += __shfl_xor(f3, o);
  }
  x0 += f0 + bf2[0]; x1 += f1 + bf2[1]; x2 += f2 + bf2[2]; x3 += f3 + bf2[3];
  if (dofinal) {
    if (lane < NT_)
      out[tok * NT_ + lane] = bout[lane] + x0 * Wout[lane] + x1 * Wout[NT_ + lane] +
                              x2 * Wout[2 * NT_ + lane] + x3 * Wout[3 * NT_ + lane];
    return;
  }
  if (lane == 0) *(float4*)&x[tok * 4] = make_float4(x0, x1, x2, x3);
  if (doinln) {
    float xp[8];
    float s = 0.f, qs = 0.f;
#pragma unroll
    for (int k = 0; k < 8; k++) {
      int jj = 64 * k + lane;
      float v = bi[jj] + x0 * Wi[jj] + x1 * Wi[H_ + jj] + x2 * Wi[2 * H_ + jj] + x3 * Wi[3 * H_ + jj];
      xp[k] = v;
      s += v;
      qs += v * v;
    }
#pragma unroll
    for (int o = 1; o < 64; o <<= 1) {
      s += __shfl_xor(s, o);
      qs += __shfl_xor(qs, o);
    }
    float mean = s * (1.f / (float)H_);
    float var1 = qs * (1.f / (float)H_) - mean * mean;
    float rs1 = rsqrtf(var1 + EPS_);
#pragma unroll
    for (int k = 0; k < 8; k++) {
      int jj = 64 * k + lane;
      float v = (xp[k] - mean) * rs1 * g1[jj] + b1n[jj];
      xnbf[tok * H_ + jj] = bf16_rne(v);
    }
  }
}

extern "C" void kernel_launch(void* const* d_in, const int* in_sizes, int n_in,
                              void* d_out, int out_size, void* d_ws, size_t ws_size,
                              hipStream_t stream) {
  const int* patches = (const int*)d_in[0];
  const int* mask = (const int*)d_in[1];
  const float* emb = (const float*)d_in[2];
  const float* Wi = (const float*)d_in[3];
  const float* bi = (const float*)d_in[4];
  const float* Wqkv = (const float*)d_in[5];
  const float* bqkv = (const float*)d_in[6];
  const float* Wo = (const float*)d_in[7];
  const float* bo = (const float*)d_in[8];
  const float* g1 = (const float*)d_in[9];
  const float* b1n = (const float*)d_in[10];
  const float* Wf1 = (const float*)d_in[11];
  const float* bf1 = (const float*)d_in[12];
  const float* Wf2 = (const float*)d_in[13];
  const float* bf2 = (const float*)d_in[14];
  const float* g2 = (const float*)d_in[15];
  const float* b2n = (const float*)d_in[16];
  const float* relemb = (const float*)d_in[17];
  const float* Wout = (const float*)d_in[18];
  const float* bout = (const float*)d_in[19];
  float* out = (float*)d_out;

  char* p = (char*)d_ws;
  float* x = (float*)p;          p += (size_t)BS_ * 4 * 4;
  float* T = (float*)p;          p += (size_t)L_ * 2112 * 4;
  float* negT = (float*)p;       p += (size_t)BS_ * 4;
  float* AOp = (float*)p;        p += (size_t)KSPLIT_ * BS_ * NH_ * 4 * 4;
  float* lpart = (float*)p;      p += (size_t)KSPLIT_ * 32 * 1024 * 4;
  ushort* xnbf = (ushort*)p;     p += (size_t)BS_ * H_ * 2;
  ushort* Wt = (ushort*)p;       p += (size_t)L_ * 1536 * 512 * 2;
  ushort* qf = (ushort*)p;       p += (size_t)32 * 1024 * 64 * 2;
  ushort* kf = (ushort*)p;       p += (size_t)32 * 1024 * 64 * 2;
  ushort* vf = (ushort*)p;       p += (size_t)32 * 64 * 1024 * 2;

  k_pre<<<dim3(1841), dim3(256), 0, stream>>>(patches, mask, emb, relemb, Wqkv,
                                              Wi, bi, g1, b1n, x, T, negT, Wt, xnbf);
  for (int l = 0; l < L_; l++) {
    k_qkv<<<dim3(12, 32), dim3(256), 0, stream>>>(xnbf, Wt + (size_t)l * 1536 * 512,
                                                  bqkv + l * 3 * H_, qf, kf, vf);
    k_attn<<<dim3(1024), dim3(256), 0, stream>>>(qf, kf, vf, T + l * 2112, negT,
                                                 Wo + l * H_ * E_, AOp, lpart);
    int nl = l + 1;
    k_resffn<<<dim3(1024), dim3(256), 0, stream>>>(
        AOp, lpart, bo + l * E_, g2 + l * E_, b2n + l * E_,
        Wf1 + l * E_ * FF_, bf1 + l * FF_, Wf2 + l * FF_ * E_, bf2 + l * E_, x,
        Wi + nl * E_ * H_, bi + nl * H_, g1 + nl * H_, b1n + nl * H_, xnbf,
        (l < L_ - 1) ? 1 : 0, Wout, bout, out, (l == L_ - 1) ? 1 : 0);
  }
}

// Round 18
// 331.072 us; speedup vs baseline: 1.0144x; 1.0144x over previous
//
#include <hip/hip_runtime.h>
#include <hip/hip_bf16.h>
#include <math.h>

#define B_ 4
#define S_ 1024
#define H_ 512
#define NH_ 8
#define HD_ 64
#define FF_ 1024
#define E_ 4
#define L_ 4
#define NT_ 17
#define BS_ 4096
#define EPS_ 1e-5f
#define L2E_ 1.4426950408889634f
#define SCL_ 0.18033688011112042f   // 0.125 * log2(e)
#define KSPLIT_ 4

typedef __attribute__((ext_vector_type(8))) short short8;
typedef __attribute__((ext_vector_type(16))) float f32x16;
typedef float float4u __attribute__((ext_vector_type(4), aligned(4)));

__device__ inline ushort bf16_rne(float f) {
  unsigned u = __builtin_bit_cast(unsigned, f);
  u += 0x7FFFu + ((u >> 16) & 1u);
  return (ushort)(u >> 16);
}
__device__ inline unsigned pk_bf16(float a, float b) {
  return (unsigned)bf16_rne(a) | ((unsigned)bf16_rne(b) << 16);
}
// fast pack: round-half-away + v_perm_b32 (3 VALU ops)
__device__ inline unsigned pk2(float a, float b) {
  unsigned ua = __builtin_bit_cast(unsigned, a) + 0x8000u;
  unsigned ub = __builtin_bit_cast(unsigned, b) + 0x8000u;
  return __builtin_amdgcn_perm(ub, ua, 0x07060302u);
}
__device__ inline float ubf2f(ushort u) {
  return __builtin_bit_cast(float, ((unsigned)u) << 16);
}

// frag32 layout: a [32 rows]x[16 k] bf16 tile stored as 64 lanes x 8 ushort;
// lane (hh*32+lq) holds row lq, k = hh*8..hh*8+7.  One tile = 1024 B, loaded
// by a wave as a single coalesced 16B/lane read.  Serves both MFMA A and B
// operands of 32x32x16 (their lane->element maps coincide).

// ---------------------------------------------------------------------------
// k_pre: fused one-time prologue (block-range dispatch).
//   bid in [0,768):     cvtw — Wqkv fp32 -> Wt bf16 [l][n][k] (LDS transpose)
//   bid in [768,817):   init — x/negT/T tables
//   bid in [817,1841):  inln layer 0 — wave/token, direct emb gather
// ---------------------------------------------------------------------------
__global__ __launch_bounds__(256) void k_pre(const int* __restrict__ patches,
                                             const int* __restrict__ mask,
                                             const float* __restrict__ emb,
                                             const float* __restrict__ relemb,
                                             const float* __restrict__ W,
                                             const float* __restrict__ Wi,
                                             const float* __restrict__ bi,
                                             const float* __restrict__ g1,
                                             const float* __restrict__ b1n,
                                             float* __restrict__ x,
                                             float* __restrict__ T,
                                             float* __restrict__ negT,
                                             ushort* __restrict__ Wt,
                                             ushort* __restrict__ xnbf) {
  __shared__ ushort Tr[64][72];
  int bid = blockIdx.x, t = threadIdx.x;
  if (bid < 768) {
    int l = bid / 192, rem = bid % 192;
    int k0 = (rem / 24) * 64, n0 = (rem % 24) * 64;
    const float* src = W + (size_t)l * 512 * 1536;
    int row = t >> 4, c4 = (t & 15) * 4;
#pragma unroll
    for (int rr = 0; rr < 4; rr++) {
      int k = rr * 16 + row;
      float4 v = *(const float4*)(src + (size_t)(k0 + k) * 1536 + n0 + c4);
      Tr[c4 + 0][k] = bf16_rne(v.x);
      Tr[c4 + 1][k] = bf16_rne(v.y);
      Tr[c4 + 2][k] = bf16_rne(v.z);
      Tr[c4 + 3][k] = bf16_rne(v.w);
    }
    __syncthreads();
    int nrow = t >> 2, kc = (t & 3) * 16;
    ushort* dst = Wt + ((size_t)(l * 1536 + n0 + nrow)) * 512 + k0 + kc;
    *(uint4*)dst = *(uint4*)&Tr[nrow][kc];
    *(uint4*)(dst + 8) = *(uint4*)&Tr[nrow][kc + 8];
  } else if (bid < 817) {
    int gid = (bid - 768) * 256 + t;
    if (gid < BS_) {
      int mk = mask[gid];
      int row = mk ? (NT_ - 1) : patches[gid];
      ((float4*)x)[gid] = ((const float4*)emb)[row];
      negT[gid] = mk ? -1e30f : 0.f;
    } else {
      int idx = gid - BS_;
      if (idx < L_ * 2112) {
        int l = idx / 2112, j = idx - l * 2112;
        int c = 1086 - j;
        c = c < 0 ? 0 : (c > 62 ? 62 : c);
        const float* src = relemb + (size_t)(l * 63 + c) * 64;
        float s = 0.f;
#pragma unroll
        for (int d = 0; d < 64; d++) s += src[d];
        T[idx] = s * L2E_;
      }
    }
  } else {
    int token = (bid - 817) * 4 + (t >> 6);
    int lane = t & 63;
    int mk = mask[token];
    int row = mk ? (NT_ - 1) : patches[token];
    float4 e = ((const float4*)emb)[row];
    float xp[8];
    float s = 0.f, qs = 0.f;
#pragma unroll
    for (int k = 0; k < 8; k++) {
      int jj = 64 * k + lane;
      float v = bi[jj] + e.x * Wi[jj] + e.y * Wi[H_ + jj] + e.z * Wi[2 * H_ + jj] + e.w * Wi[3 * H_ + jj];
      xp[k] = v; s += v; qs += v * v;
    }
#pragma unroll
    for (int o = 1; o < 64; o <<= 1) { s += __shfl_xor(s, o); qs += __shfl_xor(qs, o); }
    float mean = s * (1.f / (float)H_);
    float var = qs * (1.f / (float)H_) - mean * mean;
    float rs = rsqrtf(var + EPS_);
#pragma unroll
    for (int k = 0; k < 8; k++) {
      int jj = 64 * k + lane;
      xnbf[token * H_ + jj] = bf16_rne((xp[k] - mean) * rs * g1[jj] + b1n[jj]);
    }
  }
}

// ---------------------------------------------------------------------------
// k_qkv: bf16 MFMA GEMM; 128x128 tile, BK=64.  Register-prefetch + double-
// buffered LDS, one barrier per K-step.  Epilogues write q/k/v frag32.
// ---------------------------------------------------------------------------
__global__ __launch_bounds__(256, 2) void k_qkv(const ushort* __restrict__ A,
                                                const ushort* __restrict__ Wt,
                                                const float* __restrict__ bias,
                                                ushort* __restrict__ qf,
                                                ushort* __restrict__ kf,
                                                ushort* __restrict__ vf) {
  __shared__ ushort At[2][128][72];
  __shared__ ushort Bt[2][128][72];
  int t = threadIdx.x;
  int n0 = blockIdx.x * 128, m0 = blockIdx.y * 128;
  bool tr = (n0 < 1024);
  int w = t >> 6, lq = t & 31, hh = (t >> 5) & 1;
  int wm = (w & 1) * 64, wn = (w >> 1) * 64;
  f32x16 acc[2][2];
#pragma unroll
  for (int mt = 0; mt < 2; mt++)
#pragma unroll
    for (int nt = 0; nt < 2; nt++)
#pragma unroll
      for (int i = 0; i < 16; i++) acc[mt][nt][i] = 0.f;

  uint4 ar[4], br[4];

#define QLOADREGS(k0_)                                                         \
  {                                                                            \
    _Pragma("unroll") for (int j = 0; j < 4; j++) {                            \
      int idl = 256 * j + t;                                                   \
      int row = idl >> 3, u = idl & 7;                                         \
      ar[j] = *(const uint4*)(A + (size_t)(m0 + row) * 512 + (k0_) + u * 8);   \
      br[j] = *(const uint4*)(Wt + (size_t)(n0 + row) * 512 + (k0_) + u * 8);  \
    }                                                                          \
  }
#define QWRITELDS(buf_)                                                        \
  {                                                                            \
    _Pragma("unroll") for (int j = 0; j < 4; j++) {                            \
      int idl = 256 * j + t;                                                   \
      int row = idl >> 3, u = idl & 7;                                         \
      *(uint4*)&At[buf_][row][u * 8] = ar[j];                                  \
      *(uint4*)&Bt[buf_][row][u * 8] = br[j];                                  \
    }                                                                          \
  }

  QLOADREGS(0);
  QWRITELDS(0);
  __syncthreads();

  for (int it = 0; it < 8; it++) {
    int buf = it & 1;
    if (it < 7) { QLOADREGS((it + 1) * 64); }
#pragma unroll
    for (int kc = 0; kc < 4; kc++) {
      short8 af[2], bf[2];
#pragma unroll
      for (int mt = 0; mt < 2; mt++) af[mt] = *(const short8*)&At[buf][wm + mt * 32 + lq][kc * 16 + hh * 8];
#pragma unroll
      for (int nt = 0; nt < 2; nt++) bf[nt] = *(const short8*)&Bt[buf][wn + nt * 32 + lq][kc * 16 + hh * 8];
#pragma unroll
      for (int mt = 0; mt < 2; mt++)
#pragma unroll
        for (int nt = 0; nt < 2; nt++) {
          if (tr)
            acc[mt][nt] = __builtin_amdgcn_mfma_f32_32x32x16_bf16(bf[nt], af[mt], acc[mt][nt], 0, 0, 0);
          else
            acc[mt][nt] = __builtin_amdgcn_mfma_f32_32x32x16_bf16(af[mt], bf[nt], acc[mt][nt], 0, 0, 0);
        }
    }
    if (it < 7) {
      QWRITELDS(buf ^ 1);
      __syncthreads();
    }
  }
#undef QLOADREGS
#undef QWRITELDS

  if (tr) {
#pragma unroll
    for (int mt = 0; mt < 2; mt++) {
      int token = m0 + wm + mt * 32 + lq;
      int bb = token >> 10, sr = token & 1023;
      int qt = sr >> 5, lqp = sr & 31;
#pragma unroll
      for (int nt = 0; nt < 2; nt++) {
        int nn = n0 + wn + nt * 32;
        int nloc = (nn < 512) ? nn : nn - 512;
        ushort* dst = (nn < 512) ? qf : kf;
        int hd = nloc >> 6;
        int bh = bb * 8 + hd;
        size_t fragbase = ((size_t)(bh * 32 + qt)) * 4 * 512;
#pragma unroll
        for (int rg = 0; rg < 4; rg++) {
          int nbase = nn + rg * 8 + hh * 4;
          float4 bv = *(const float4*)(bias + nbase);
          float v0 = acc[mt][nt][rg * 4 + 0] + bv.x;
          float v1 = acc[mt][nt][rg * 4 + 1] + bv.y;
          float v2 = acc[mt][nt][rg * 4 + 2] + bv.z;
          float v3 = acc[mt][nt][rg * 4 + 3] + bv.w;
          int d0 = (nloc & 63) + rg * 8 + hh * 4;
          size_t addr = fragbase + (size_t)(d0 >> 4) * 512 +
                        (size_t)(((d0 >> 3) & 1) * 32 + lqp) * 8 + (d0 & 7);
          *(uint2*)(dst + addr) = make_uint2(pk_bf16(v0, v1), pk_bf16(v2, v3));
        }
      }
    }
  } else {
#pragma unroll
    for (int nt = 0; nt < 2; nt++) {
      int n = n0 + wn + nt * 32 + lq;
      int nloc = n - 1024;
      int hd = nloc >> 6, d = nloc & 63;
      float bb_ = bias[n];
#pragma unroll
      for (int mt = 0; mt < 2; mt++) {
#pragma unroll
        for (int rg = 0; rg < 4; rg++) {
          int tb = m0 + wm + mt * 32 + rg * 8 + hh * 4;
          int bb = tb >> 10, sr = tb & 1023;
          int bh = bb * 8 + hd;
          float v0 = acc[mt][nt][rg * 4 + 0] + bb_;
          float v1 = acc[mt][nt][rg * 4 + 1] + bb_;
          float v2 = acc[mt][nt][rg * 4 + 2] + bb_;
          float v3 = acc[mt][nt][rg * 4 + 3] + bb_;
          size_t addr = ((size_t)((bh * 2 + (d >> 5)) * 64 + (sr >> 4))) * 512 +
                        (size_t)(((sr >> 3) & 1) * 32 + (d & 31)) * 8 + (sr & 7);
          *(uint2*)(vf + addr) = make_uint2(pk_bf16(v0, v1), pk_bf16(v2, v3));
        }
      }
    }
  }
}

// ---------------------------------------------------------------------------
// k_attn: bf16 MFMA attention, S^T form, fixed-scale softmax.  4 waves/block
// sharing a K/V chunk; KSPLIT=4 (1024 blocks), zero __syncthreads.
// Epilogue fuses Wo; private j-slot float4 partials (no atomics).
// (R17's register K-prefetch was neutral -- TLP at 4 waves/SIMD already
// covers the K-load latency; reverted to keep VGPR pressure low.)
// ---------------------------------------------------------------------------
__global__ __launch_bounds__(256, 3) void k_attn(const ushort* __restrict__ qf,
                                                 const ushort* __restrict__ kf,
                                                 const ushort* __restrict__ vf,
                                                 const float* __restrict__ Tl,
                                                 const float* __restrict__ negT,
                                                 const float* __restrict__ Wol,
                                                 float* __restrict__ AOp,
                                                 float* __restrict__ lpart) {
  __shared__ ushort Pt[4][32][72];
  int t = threadIdx.x;
  int w = t >> 6, lane = t & 63;
  int lq = lane & 31, hh = lane >> 5;
  int id = blockIdx.x;
  int bh = id & 31;
  int slot = id >> 5;
  int qtg = slot & 7, j = slot >> 3;
  int b = bh >> 3, head = bh & 7;
  int qt = qtg * 4 + w;
  int q = qt * 32 + lq;
  int kstart = j * 256;

  const ushort* qbase = qf + ((size_t)(bh * 32 + qt)) * 2048 + lane * 8;
  short8 Qf[4];
#pragma unroll
  for (int c = 0; c < 4; c++) Qf[c] = *(const short8*)(qbase + c * 512);

  float Tlo = Tl[1086];
  float Thi = Tl[1024];

  float l_run = 0.f;
  f32x16 Ot[2];
#pragma unroll
  for (int dt = 0; dt < 2; dt++)
#pragma unroll
    for (int i = 0; i < 16; i++) Ot[dt][i] = 0.f;

  for (int it = 0; it < 4; it++) {
    int k0 = kstart + it * 64;
    short8 Kb[2][4];
#pragma unroll
    for (int st = 0; st < 2; st++) {
      const ushort* kb = kf + ((size_t)(bh * 32 + (k0 >> 5) + st)) * 2048 + lane * 8;
#pragma unroll
      for (int c = 0; c < 4; c++) Kb[st][c] = *(const short8*)(kb + c * 512);
    }
    short8 Vb[2][4];
#pragma unroll
    for (int dt = 0; dt < 2; dt++) {
      const ushort* vb = vf + ((size_t)((bh * 2 + dt) * 64 + (k0 >> 4))) * 512 + lane * 8;
#pragma unroll
      for (int c = 0; c < 4; c++) Vb[dt][c] = *(const short8*)(vb + c * 512);
    }
    // ---- S^T ----
    f32x16 sa[2];
#pragma unroll
    for (int st = 0; st < 2; st++) {
      f32x16 a;
#pragma unroll
      for (int i = 0; i < 16; i++) a[i] = 0.f;
#pragma unroll
      for (int c = 0; c < 4; c++)
        a = __builtin_amdgcn_mfma_f32_32x32x16_bf16(Kb[st][c], Qf[c], a, 0, 0, 0);
      sa[st] = a;
    }
    // ---- softmax: band-specialized ----
#pragma unroll
    for (int st = 0; st < 2; st++) {
      int kt0 = k0 + st * 32;
      int delta = kt0 - qt * 32;
      if (delta >= 64 || delta <= -64) {
        float bconst = (delta >= 64) ? Tlo : Thi;
#pragma unroll
        for (int rg = 0; rg < 4; rg++) {
          int krun = kt0 + rg * 8 + hh * 4;
          float4 nv = *(const float4*)(negT + b * S_ + krun);
          float p0 = exp2f(fmaf(sa[st][rg * 4 + 0], SCL_, bconst + nv.x));
          float p1 = exp2f(fmaf(sa[st][rg * 4 + 1], SCL_, bconst + nv.y));
          float p2 = exp2f(fmaf(sa[st][rg * 4 + 2], SCL_, bconst + nv.z));
          float p3 = exp2f(fmaf(sa[st][rg * 4 + 3], SCL_, bconst + nv.w));
          l_run += (p0 + p1) + (p2 + p3);
          *(uint2*)&Pt[w][lq][st * 32 + rg * 8 + hh * 4] = make_uint2(pk2(p0, p1), pk2(p2, p3));
        }
      } else {
#pragma unroll
        for (int rg = 0; rg < 4; rg++) {
          int krun = kt0 + rg * 8 + hh * 4;
          float4u bv = *(const float4u*)(Tl + (krun - q + 31 + 1024));
          float4 nv = *(const float4*)(negT + b * S_ + krun);
          float p[4];
#pragma unroll
          for (int i = 0; i < 4; i++) {
            float nvi = (i == 0) ? nv.x : (i == 1) ? nv.y : (i == 2) ? nv.z : nv.w;
            float t0 = (krun + i == q) ? bv[i] : (bv[i] + nvi);
            p[i] = exp2f(fmaf(sa[st][rg * 4 + i], SCL_, t0));
            l_run += p[i];
          }
          *(uint2*)&Pt[w][lq][st * 32 + rg * 8 + hh * 4] = make_uint2(pk2(p[0], p[1]), pk2(p[2], p[3]));
        }
      }
    }
    // ---- O^T += V^T . P ----
    short8 Pf[4];
#pragma unroll
    for (int c = 0; c < 4; c++) Pf[c] = *(const short8*)&Pt[w][lq][c * 16 + hh * 8];
#pragma unroll
    for (int dt = 0; dt < 2; dt++)
#pragma unroll
      for (int c = 0; c < 4; c++)
        Ot[dt] = __builtin_amdgcn_mfma_f32_32x32x16_bf16(Vb[dt][c], Pf[c], Ot[dt], 0, 0, 0);
  }
  // ---- epilogue: project through Wo[head], store private j-slot partial ----
  const float* woh = Wol + head * 64 * 4;
  float pe0 = 0.f, pe1 = 0.f, pe2 = 0.f, pe3 = 0.f;
#pragma unroll
  for (int dt = 0; dt < 2; dt++)
#pragma unroll
    for (int rg = 0; rg < 4; rg++)
#pragma unroll
      for (int i = 0; i < 4; i++) {
        int d = dt * 32 + rg * 8 + hh * 4 + i;
        float4 wv = *(const float4*)(woh + d * 4);
        float o = Ot[dt][rg * 4 + i];
        pe0 = fmaf(o, wv.x, pe0);
        pe1 = fmaf(o, wv.y, pe1);
        pe2 = fmaf(o, wv.z, pe2);
        pe3 = fmaf(o, wv.w, pe3);
      }
  pe0 += __shfl_xor(pe0, 32);
  pe1 += __shfl_xor(pe1, 32);
  pe2 += __shfl_xor(pe2, 32);
  pe3 += __shfl_xor(pe3, 32);
  float l_tot = l_run + __shfl_xor(l_run, 32);
  if (hh == 0) {
    float* ao = AOp + (size_t)j * (BS_ * NH_ * 4) + ((size_t)(b * S_ + q) * NH_ + head) * 4;
    *(float4*)ao = make_float4(pe0, pe1, pe2, pe3);
    lpart[((size_t)j * 32 + bh) * S_ + q] = l_tot;
  }
}

// ---------------------------------------------------------------------------
// k_resffn: combine j-slot partials per head, sum heads, x += ao + bo,
// ln2(E=4), FFN, residual.  doinln: fuse next layer's inproj+LN.
// dofinal: out = x@Wout+bout.
// ---------------------------------------------------------------------------
__global__ __launch_bounds__(256) void k_resffn(const float* __restrict__ AOp,
                                                const float* __restrict__ lpart,
                                                const float* __restrict__ bo,
                                                const float* __restrict__ g2,
                                                const float* __restrict__ b2n,
                                                const float* __restrict__ Wf1,
                                                const float* __restrict__ bf1,
                                                const float* __restrict__ Wf2,
                                                const float* __restrict__ bf2,
                                                float* __restrict__ x,
                                                const float* __restrict__ Wi,
                                                const float* __restrict__ bi,
                                                const float* __restrict__ g1,
                                                const float* __restrict__ b1n,
                                                ushort* __restrict__ xnbf,
                                                int doinln,
                                                const float* __restrict__ Wout,
                                                const float* __restrict__ bout,
                                                float* __restrict__ out,
                                                int dofinal) {
  int tok = blockIdx.x * 4 + (threadIdx.x >> 6);
  int lane = threadIdx.x & 63;
  int b = tok >> 10, qq = tok & 1023;
  int h = lane & 7;
  int lidx = (b * 8 + h) * 1024 + qq;
  float ls = lpart[lidx] + lpart[lidx + 32768] + lpart[lidx + 65536] + lpart[lidx + 98304];
  float inv = 1.f / ls;
  size_t abase = ((size_t)tok * 8 + h) * 4;
  float4 v0 = *(const float4*)(AOp + abase);
  float4 v1 = *(const float4*)(AOp + abase + 131072);
  float4 v2 = *(const float4*)(AOp + abase + 262144);
  float4 v3 = *(const float4*)(AOp + abase + 393216);
  float r0 = (v0.x + v1.x + v2.x + v3.x) * inv;
  float r1 = (v0.y + v1.y + v2.y + v3.y) * inv;
  float r2 = (v0.z + v1.z + v2.z + v3.z) * inv;
  float r3 = (v0.w + v1.w + v2.w + v3.w) * inv;
#pragma unroll
  for (int o = 1; o < 8; o <<= 1) {
    r0 += __shfl_xor(r0, o); r1 += __shfl_xor(r1, o);
    r2 += __shfl_xor(r2, o); r3 += __shfl_xor(r3, o);
  }
  float4 xo = *(const float4*)&x[tok * 4];
  float x0 = xo.x + r0 + bo[0];
  float x1 = xo.y + r1 + bo[1];
  float x2 = xo.z + r2 + bo[2];
  float x3 = xo.w + r3 + bo[3];
  float mn = 0.25f * (x0 + x1 + x2 + x3);
  float d0 = x0 - mn, d1 = x1 - mn, d2 = x2 - mn, d3 = x3 - mn;
  float var = 0.25f * (d0 * d0 + d1 * d1 + d2 * d2 + d3 * d3);
  float rs = rsqrtf(var + EPS_);
  float l0 = d0 * rs * g2[0] + b2n[0];
  float l1 = d1 * rs * g2[1] + b2n[1];
  float l2 = d2 * rs * g2[2] + b2n[2];
  float l3 = d3 * rs * g2[3] + b2n[3];
  float f0 = 0, f1 = 0, f2 = 0, f3 = 0;
#pragma unroll
  for (int f4 = 0; f4 < FF_ / 64; f4++) {
    int f = lane + f4 * 64;
    float hh = bf1[f] + l0 * Wf1[f] + l1 * Wf1[FF_ + f] + l2 * Wf1[2 * FF_ + f] + l3 * Wf1[3 * FF_ + f];
    hh = fmaxf(hh, 0.f);
    float4 w2 = *(const float4*)&Wf2[f * 4];
    f0 += hh * w2.x; f1 += hh * w2.y; f2 += hh * w2.z; f3 += hh * w2.w;
  }
#pragma unroll
  for (int o = 1; o < 64; o <<= 1) {
    f0 += __shfl_xor(f0, o); f1 += __shfl_xor(f1, o);
    f2 += __shfl_xor(f2, o); f3 += __shfl_xor(f3, o);
  }
  x0 += f0 + bf2[0]; x1 += f1 + bf2[1]; x2 += f2 + bf2[2]; x3 += f3 + bf2[3];
  if (dofinal) {
    if (lane < NT_)
      out[tok * NT_ + lane] = bout[lane] + x0 * Wout[lane] + x1 * Wout[NT_ + lane] +
                              x2 * Wout[2 * NT_ + lane] + x3 * Wout[3 * NT_ + lane];
    return;
  }
  if (lane == 0) *(float4*)&x[tok * 4] = make_float4(x0, x1, x2, x3);
  if (doinln) {
    float xp[8];
    float s = 0.f, qs = 0.f;
#pragma unroll
    for (int k = 0; k < 8; k++) {
      int jj = 64 * k + lane;
      float v = bi[jj] + x0 * Wi[jj] + x1 * Wi[H_ + jj] + x2 * Wi[2 * H_ + jj] + x3 * Wi[3 * H_ + jj];
      xp[k] = v;
      s += v;
      qs += v * v;
    }
#pragma unroll
    for (int o = 1; o < 64; o <<= 1) {
      s += __shfl_xor(s, o);
      qs += __shfl_xor(qs, o);
    }
    float mean = s * (1.f / (float)H_);
    float var1 = qs * (1.f / (float)H_) - mean * mean;
    float rs1 = rsqrtf(var1 + EPS_);
#pragma unroll
    for (int k = 0; k < 8; k++) {
      int jj = 64 * k + lane;
      float v = (xp[k] - mean) * rs1 * g1[jj] + b1n[jj];
      xnbf[tok * H_ + jj] = bf16_rne(v);
    }
  }
}

extern "C" void kernel_launch(void* const* d_in, const int* in_sizes, int n_in,
                              void* d_out, int out_size, void* d_ws, size_t ws_size,
                              hipStream_t stream) {
  const int* patches = (const int*)d_in[0];
  const int* mask = (const int*)d_in[1];
  const float* emb = (const float*)d_in[2];
  const float* Wi = (const float*)d_in[3];
  const float* bi = (const float*)d_in[4];
  const float* Wqkv = (const float*)d_in[5];
  const float* bqkv = (const float*)d_in[6];
  const float* Wo = (const float*)d_in[7];
  const float* bo = (const float*)d_in[8];
  const float* g1 = (const float*)d_in[9];
  const float* b1n = (const float*)d_in[10];
  const float* Wf1 = (const float*)d_in[11];
  const float* bf1 = (const float*)d_in[12];
  const float* Wf2 = (const float*)d_in[13];
  const float* bf2 = (const float*)d_in[14];
  const float* g2 = (const float*)d_in[15];
  const float* b2n = (const float*)d_in[16];
  const float* relemb = (const float*)d_in[17];
  const float* Wout = (const float*)d_in[18];
  const float* bout = (const float*)d_in[19];
  float* out = (float*)d_out;

  char* p = (char*)d_ws;
  float* x = (float*)p;          p += (size_t)BS_ * 4 * 4;
  float* T = (float*)p;          p += (size_t)L_ * 2112 * 4;
  float* negT = (float*)p;       p += (size_t)BS_ * 4;
  float* AOp = (float*)p;        p += (size_t)KSPLIT_ * BS_ * NH_ * 4 * 4;
  float* lpart = (float*)p;      p += (size_t)KSPLIT_ * 32 * 1024 * 4;
  ushort* xnbf = (ushort*)p;     p += (size_t)BS_ * H_ * 2;
  ushort* Wt = (ushort*)p;       p += (size_t)L_ * 1536 * 512 * 2;
  ushort* qf = (ushort*)p;       p += (size_t)32 * 1024 * 64 * 2;
  ushort* kf = (ushort*)p;       p += (size_t)32 * 1024 * 64 * 2;
  ushort* vf = (ushort*)p;       p += (size_t)32 * 64 * 1024 * 2;

  k_pre<<<dim3(1841), dim3(256), 0, stream>>>(patches, mask, emb, relemb, Wqkv,
                                              Wi, bi, g1, b1n, x, T, negT, Wt, xnbf);
  for (int l = 0; l < L_; l++) {
    k_qkv<<<dim3(12, 32), dim3(256), 0, stream>>>(xnbf, Wt + (size_t)l * 1536 * 512,
                                                  bqkv + l * 3 * H_, qf, kf, vf);
    k_attn<<<dim3(1024), dim3(256), 0, stream>>>(qf, kf, vf, T + l * 2112, negT,
                                                 Wo + l * H_ * E_, AOp, lpart);
    int nl = l + 1;
    k_resffn<<<dim3(1024), dim3(256), 0, stream>>>(
        AOp, lpart, bo + l * E_, g2 + l * E_, b2n + l * E_,
        Wf1 + l * E_ * FF_, bf1 + l * FF_, Wf2 + l * FF_ * E_, bf2 + l * E_, x,
        Wi + nl * E_ * H_, bi + nl * H_, g1 + nl * H_, b1n + nl * H_, xnbf,
        (l < L_ - 1) ? 1 : 0, Wout, bout, out, (l == L_ - 1) ? 1 : 0);
  }
}